// Round 7
// baseline (254.268 us; speedup 1.0000x reference)
//
#include <hip/hip_runtime.h>

#define S 28
#define BB 2
#define NC 80
#define MAXB 50
#define CH (BB*5+NC)   // 90
#define BLOCK 256
#define SENT 0x7E57C0DEu   // != 0xAAAAAAAA harness poison, != 0

__device__ __constant__ float kCell = 1.0f / (float)S;

static constexpr float LAMBDA_COORD = 5.0f;
static constexpr float LAMBDA_NOOBJ = 0.1f;
static constexpr float EPS_IOU = 1e-6f;
static constexpr float EPSF    = 1e-7f;
static constexpr double PI_D   = 3.141592653589793;
static constexpr float FOUR_OVER_PI2 = (float)(4.0 / (PI_D * PI_D));

// Single fused kernel, single dispatch.
// Thread tid: branchless noobj conf^2 for cell tid.
// 16-lane group gid = (b,t): scan the image's 50 targets (lane-strided),
// filter to same cell, compute each candidate's best-IoU (bit-identical
// f32 replay), reduce winner key + class-bit union in-registers.
// Winner group (low32(key) == MAXB-t) adds BCE + CIoU + conf terms.
// Completion: each block stores partial, fence, release-store SENT flag,
// exits (never waits on a later block -> deadlock-free under any dispatch
// order). Last-indexed block's wave 0 acquire-polls all flags, sums
// partials, writes out[0]. Flags distinguishable from harness 0xAA poison.
__global__ void __launch_bounds__(BLOCK)
yolo_loss_k(const float* __restrict__ pred,
            const float* __restrict__ targ,
            float* __restrict__ partial,
            unsigned int* __restrict__ flags,
            float* __restrict__ out,
            int batch, float inv_batch) {
    int tid = blockIdx.x * BLOCK + threadIdx.x;
    int ncells = batch * S * S;
    int nt = batch * MAXB;
    float tot = 0.0f;
    const float cell = kCell;

    // --- branchless noobj conf stream (every cell, both boxes) ---
    if (tid < ncells) {
        const float* p = pred + (size_t)tid * CH;
        float c0 = p[4];
        float c1 = p[9];
        tot = LAMBDA_NOOBJ * (c0 * c0 + c1 * c1);
    }

    // --- per-target group work ---
    int gid    = tid >> 4;
    int lane16 = tid & 15;
    if (gid < nt) {
        int b = gid / MAXB;
        int t = gid - b * MAXB;
        const float* tg = targ + (size_t)gid * 5;
        float cls = tg[0];
        if (cls >= 0.0f) {  // uniform across the 16-lane group
            float cx = tg[1], cy = tg[2], gw = tg[3], gh = tg[4];
            float cxs = cx / cell;
            float cys = cy / cell;
            int col = min((int)cxs, S - 1);
            int row = min((int)cys, S - 1);
            size_t cellidx = ((size_t)b * S + row) * S + col;
            const float* p = pred + cellidx * CH;

            // ---- local winner scan over this image's targets ----
            const float* timg = targ + (size_t)b * MAXB * 5;
            unsigned long long bestkey = 0ull;
            unsigned m0 = 0, m1 = 0, m2 = 0;
            for (int tt = lane16; tt < MAXB; tt += 16) {
                const float* tg2 = timg + tt * 5;
                float c2 = tg2[0];
                if (c2 < 0.0f) continue;
                float cx2 = tg2[1], cy2 = tg2[2], w2 = tg2[3], h2 = tg2[4];
                int col2 = min((int)(cx2 / cell), S - 1);
                int row2 = min((int)(cy2 / cell), S - 1);
                if (col2 != col || row2 != row) continue;
                int cid = max(0, min((int)c2, NC - 1));
                if (cid < 32)      m0 |= 1u << cid;
                else if (cid < 64) m1 |= 1u << (cid - 32);
                else               m2 |= 1u << (cid - 64);
                // best-IoU of the cell's 2 pred boxes vs this gt (exact replay)
                float gx1 = cx2 - w2 * 0.5f, gy1 = cy2 - h2 * 0.5f;
                float gx2 = cx2 + w2 * 0.5f, gy2 = cy2 + h2 * 0.5f;
                float best = -1.0f;
#pragma unroll
                for (int j = 0; j < BB; ++j) {
                    float px = (p[j * 5 + 0] + (float)col) * cell;
                    float py = (p[j * 5 + 1] + (float)row) * cell;
                    float pw = p[j * 5 + 2];
                    float ph = p[j * 5 + 3];
                    float px1 = px - pw * 0.5f, py1 = py - ph * 0.5f;
                    float px2 = px + pw * 0.5f, py2 = py + ph * 0.5f;
                    float iw = fmaxf(fminf(px2, gx2) - fmaxf(px1, gx1), 0.0f);
                    float ih = fmaxf(fminf(py2, gy2) - fmaxf(py1, gy1), 0.0f);
                    float inter = iw * ih;
                    float uni = fmaxf(px2 - px1, 0.0f) * fmaxf(py2 - py1, 0.0f)
                              + fmaxf(gx2 - gx1, 0.0f) * fmaxf(gy2 - gy1, 0.0f) - inter;
                    float iou = inter / (uni + EPS_IOU);
                    best = fmaxf(best, iou);
                }
                unsigned long long key =
                    ((unsigned long long)__float_as_uint(best) << 32) |
                    (unsigned long long)(unsigned)(MAXB - tt);
                if (key > bestkey) bestkey = key;
            }
            // in-group reduction (xor masks <16 stay within the 16-lane group)
#pragma unroll
            for (int off = 1; off < 16; off <<= 1) {
                unsigned long long ok = __shfl_xor(bestkey, off, 64);
                if (ok > bestkey) bestkey = ok;
                m0 |= __shfl_xor(m0, off, 64);
                m1 |= __shfl_xor(m1, off, 64);
                m2 |= __shfl_xor(m2, off, 64);
            }

            if ((unsigned)(bestkey & 0xffffffffu) == (unsigned)(MAXB - t)) {
                // this group's target owns the cell
                const float* pc = p + BB * 5;
                float cl = 0.0f;
#pragma unroll
                for (int j = 0; j < 5; ++j) {
                    int k = lane16 + 16 * j;
                    float x = pc[k];
                    unsigned mw = (k < 32) ? m0 : (k < 64) ? m1 : m2;
                    float gt = ((mw >> (k & 31)) & 1u) ? 1.0f : 0.0f;
                    cl += fmaxf(x, 0.0f) - x * gt + log1pf(expf(-fabsf(x)));
                }
#pragma unroll
                for (int off = 1; off < 16; off <<= 1)
                    cl += __shfl_xor(cl, off, 64);

                if (lane16 == 0) {
                    float best_iou = __uint_as_float((unsigned)(bestkey >> 32));
                    float cx_rel = cxs - (float)col;
                    float cy_rel = cys - (float)row;

                    float p0[10];
#pragma unroll
                    for (int k = 0; k < 5; ++k) {
                        float2 v2 = *(const float2*)(p + 2 * k);
                        p0[2 * k] = v2.x; p0[2 * k + 1] = v2.y;
                    }

                    // replay argmax to get resp (bit-identical)
                    float gax1 = cx - gw * 0.5f, gay1 = cy - gh * 0.5f;
                    float gax2 = cx + gw * 0.5f, gay2 = cy + gh * 0.5f;
                    float bst = -1.0f; int resp = 0;
#pragma unroll
                    for (int j = 0; j < BB; ++j) {
                        float px = (p0[j * 5 + 0] + (float)col) * cell;
                        float py = (p0[j * 5 + 1] + (float)row) * cell;
                        float pw = p0[j * 5 + 2];
                        float ph = p0[j * 5 + 3];
                        float px1 = px - pw * 0.5f, py1 = py - ph * 0.5f;
                        float px2 = px + pw * 0.5f, py2 = py + ph * 0.5f;
                        float iw = fmaxf(fminf(px2, gax2) - fmaxf(px1, gax1), 0.0f);
                        float ih = fmaxf(fminf(py2, gay2) - fmaxf(py1, gay1), 0.0f);
                        float inter = iw * ih;
                        float uni = fmaxf(px2 - px1, 0.0f) * fmaxf(py2 - py1, 0.0f)
                                  + fmaxf(gax2 - gax1, 0.0f) * fmaxf(gay2 - gay1, 0.0f) - inter;
                        float iou = inter / (uni + EPS_IOU);
                        if (iou > bst) { bst = iou; resp = j; }
                    }

                    float bx = p0[resp * 5 + 0], by = p0[resp * 5 + 1];
                    float bw = p0[resp * 5 + 2], bh = p0[resp * 5 + 3];
                    float conf_r = p0[resp * 5 + 4];

                    float pax = (bx + (float)col) * cell;
                    float pay = (by + (float)row) * cell;
                    float paw = fabsf(bw), pah = fabsf(bh);
                    float gax = (cx_rel + (float)col) * cell;
                    float gay = (cy_rel + (float)row) * cell;

                    // CIoU (EPS = 1e-7 here)
                    float px1 = pax - paw * 0.5f, py1 = pay - pah * 0.5f;
                    float px2 = pax + paw * 0.5f, py2 = pay + pah * 0.5f;
                    float gx1 = gax - gw * 0.5f,  gy1 = gay - gh * 0.5f;
                    float gx2 = gax + gw * 0.5f,  gy2 = gay + gh * 0.5f;
                    float iw = fmaxf(fminf(px2, gx2) - fmaxf(px1, gx1), 0.0f);
                    float ih = fmaxf(fminf(py2, gy2) - fmaxf(py1, gy1), 0.0f);
                    float inter = iw * ih;
                    float area_p = fmaxf(px2 - px1, 0.0f) * fmaxf(py2 - py1, 0.0f);
                    float area_g = fmaxf(gx2 - gx1, 0.0f) * fmaxf(gy2 - gy1, 0.0f);
                    float uni = area_p + area_g - inter;
                    float iou = inter / (uni + EPSF);
                    float dx = pax - gax, dy = pay - gay;
                    float rho2 = dx * dx + dy * dy;
                    float cw = fmaxf(px2, gx2) - fminf(px1, gx1);
                    float chh = fmaxf(py2, gy2) - fminf(py1, gy1);
                    float c2 = cw * cw + chh * chh + EPSF;
                    float dv = atanf(gw / (gh + EPSF)) - atanf(paw / (pah + EPSF));
                    float v = FOUR_OVER_PI2 * dv * dv;
                    float alpha = v / (1.0f - iou + v + EPSF);
                    float ciou = 1.0f - iou + rho2 / c2 + alpha * v;

                    float d = conf_r - best_iou;
                    tot += cl + LAMBDA_COORD * ciou + d * d
                         - LAMBDA_NOOBJ * conf_r * conf_r;  // undo stream term
                }
            }
        }
    }

    // block reduction -> partial[block], then release-store flag and exit
    float v = tot;
#pragma unroll
    for (int off = 32; off > 0; off >>= 1)
        v += __shfl_down(v, off, 64);
    __shared__ float red[4];
    int lane = threadIdx.x & 63;
    int wid  = threadIdx.x >> 6;
    if (lane == 0) red[wid] = v;
    __syncthreads();
    if (threadIdx.x == 0) {
        partial[blockIdx.x] = red[0] + red[1] + red[2] + red[3];
        __threadfence();  // device-scope: partial visible before flag
        __hip_atomic_store(&flags[blockIdx.x], SENT, __ATOMIC_RELEASE,
                           __HIP_MEMORY_SCOPE_AGENT);
    }

    // Last-indexed block finishes the sum. It never blocks any other block
    // (all others have exited or will exit independently) -> G16-safe.
    if (blockIdx.x == gridDim.x - 1 && threadIdx.x < 64) {
        int nblocks = gridDim.x;
        bool alldone = false;
        while (!alldone) {
            bool mine = true;
            for (int i = threadIdx.x; i < nblocks; i += 64) {
                if (__hip_atomic_load(&flags[i], __ATOMIC_ACQUIRE,
                                      __HIP_MEMORY_SCOPE_AGENT) != SENT) {
                    mine = false;
                    break;
                }
            }
            alldone = __all(mine);
        }
        float s = 0.0f;
        for (int i = threadIdx.x; i < nblocks; i += 64) {
            unsigned u = __hip_atomic_load((unsigned int*)&partial[i],
                                           __ATOMIC_RELAXED,
                                           __HIP_MEMORY_SCOPE_AGENT);
            s += __uint_as_float(u);
        }
#pragma unroll
        for (int off = 32; off > 0; off >>= 1)
            s += __shfl_down(s, off, 64);
        if (threadIdx.x == 0)
            out[0] = s * inv_batch;
    }
}

extern "C" void kernel_launch(void* const* d_in, const int* in_sizes, int n_in,
                              void* d_out, int out_size, void* d_ws, size_t ws_size,
                              hipStream_t stream) {
    const float* pred = (const float*)d_in[0];
    const float* targ = (const float*)d_in[1];
    int batch = in_sizes[0] / (S * S * CH);
    size_t ncells = (size_t)batch * S * S;
    int nt = batch * MAXB;

    // grid covers max(ncells, 16*nt); 16*MAXB=800 >= S*S=784 so 16*nt wins
    int nthreads = 16 * nt;
    if (nthreads < (int)ncells) nthreads = (int)ncells;
    int nblocks = (nthreads + BLOCK - 1) / BLOCK;

    // ws: partial[nblocks] floats | flags[nblocks] u32.
    // Flags are valid because harness re-poisons ws to 0xAA (!= SENT) before
    // every timed launch; first (pre-capture) call relies on fresh ws not
    // containing SENT (collision odds ~nblocks*2^-32, accepted).
    float* partial = (float*)d_ws;
    unsigned int* flags = (unsigned int*)((char*)d_ws + (size_t)nblocks * 4);

    yolo_loss_k<<<nblocks, BLOCK, 0, stream>>>(
        pred, targ, partial, flags, (float*)d_out, batch, 1.0f / (float)batch);
}

// Round 8
// 219.357 us; speedup vs baseline: 1.1591x; 1.1591x over previous
//
#include <hip/hip_runtime.h>

#define S 28
#define BB 2
#define NC 80
#define MAXB 50
#define CH (BB*5+NC)   // 90
#define BLOCK 256
#define NSTREAM 2048   // blocks dedicated to the coalesced conf^2 stream

__device__ __constant__ float kCell = 1.0f / (float)S;

static constexpr float LAMBDA_COORD = 5.0f;
static constexpr float LAMBDA_NOOBJ = 0.1f;
static constexpr float EPS_IOU = 1e-6f;
static constexpr float EPSF    = 1e-7f;
static constexpr double PI_D   = 3.141592653589793;
static constexpr float FOUR_OVER_PI2 = (float)(4.0 / (PI_D * PI_D));

// One dispatch, two block roles (disjoint blockIdx ranges):
//  - blocks [0, NSTREAM): grid-stride the ENTIRE pred as float4 (fully
//    coalesced, ~144 MB @ near-peak BW) and accumulate conf^2 for floats at
//    idx % 90 in {4, 9}. cell = idx/90 via magic multiply (exact).
//  - blocks [NSTREAM, NSTREAM+NG): round-5-verified per-target groups:
//    16-lane group per (b,t), local winner scan (bit-identical IoU replay),
//    BCE + CIoU + conf terms, minus LAMBDA_NOOBJ*conf_r^2 (undo stream).
// Both roles end with a block reduction into partial[blockIdx].
__global__ void __launch_bounds__(BLOCK)
yolo_loss_k(const float* __restrict__ pred,
            const float* __restrict__ targ,
            float* __restrict__ partial,
            int batch, int nf4) {
    float tot = 0.0f;
    const float cell = kCell;

    if (blockIdx.x < NSTREAM) {
        // ---------------- coalesced conf^2 stream ----------------
        const float4* p4 = (const float4*)pred;
        float acc = 0.0f;
        for (int f = blockIdx.x * BLOCK + threadIdx.x; f < nf4;
             f += NSTREAM * BLOCK) {
            float4 v = p4[f];
            unsigned base = 4u * (unsigned)f;
            const float* vv = &v.x;
#pragma unroll
            for (int i = 0; i < 4; ++i) {
                unsigned idx = base + i;
                unsigned c = (unsigned)(((unsigned long long)idx *
                                         3054198967ull) >> 38);  // idx/90
                unsigned r = idx - 90u * c;
                float x = vv[i];
                acc += (r == 4u || r == 9u) ? x * x : 0.0f;
            }
        }
        tot = LAMBDA_NOOBJ * acc;
    } else {
        // ---------------- per-target group work (round-5 verified) --------
        int tid = (int)(blockIdx.x - NSTREAM) * BLOCK + threadIdx.x;
        int nt = batch * MAXB;
        int gid    = tid >> 4;
        int lane16 = tid & 15;
        if (gid < nt) {
            int b = gid / MAXB;
            int t = gid - b * MAXB;
            const float* tg = targ + (size_t)gid * 5;
            float cls = tg[0];
            if (cls >= 0.0f) {  // uniform across the 16-lane group
                float cx = tg[1], cy = tg[2], gw = tg[3], gh = tg[4];
                float cxs = cx / cell;
                float cys = cy / cell;
                int col = min((int)cxs, S - 1);
                int row = min((int)cys, S - 1);
                size_t cellidx = ((size_t)b * S + row) * S + col;
                const float* p = pred + cellidx * CH;

                // ---- local winner scan over this image's targets ----
                const float* timg = targ + (size_t)b * MAXB * 5;
                unsigned long long bestkey = 0ull;
                unsigned m0 = 0, m1 = 0, m2 = 0;
                for (int tt = lane16; tt < MAXB; tt += 16) {
                    const float* tg2 = timg + tt * 5;
                    float c2 = tg2[0];
                    if (c2 < 0.0f) continue;
                    float cx2 = tg2[1], cy2 = tg2[2], w2 = tg2[3], h2 = tg2[4];
                    int col2 = min((int)(cx2 / cell), S - 1);
                    int row2 = min((int)(cy2 / cell), S - 1);
                    if (col2 != col || row2 != row) continue;
                    int cid = max(0, min((int)c2, NC - 1));
                    if (cid < 32)      m0 |= 1u << cid;
                    else if (cid < 64) m1 |= 1u << (cid - 32);
                    else               m2 |= 1u << (cid - 64);
                    // best-IoU of the cell's 2 pred boxes (exact replay)
                    float gx1 = cx2 - w2 * 0.5f, gy1 = cy2 - h2 * 0.5f;
                    float gx2 = cx2 + w2 * 0.5f, gy2 = cy2 + h2 * 0.5f;
                    float best = -1.0f;
#pragma unroll
                    for (int j = 0; j < BB; ++j) {
                        float px = (p[j * 5 + 0] + (float)col) * cell;
                        float py = (p[j * 5 + 1] + (float)row) * cell;
                        float pw = p[j * 5 + 2];
                        float ph = p[j * 5 + 3];
                        float px1 = px - pw * 0.5f, py1 = py - ph * 0.5f;
                        float px2 = px + pw * 0.5f, py2 = py + ph * 0.5f;
                        float iw = fmaxf(fminf(px2, gx2) - fmaxf(px1, gx1), 0.0f);
                        float ih = fmaxf(fminf(py2, gy2) - fmaxf(py1, gy1), 0.0f);
                        float inter = iw * ih;
                        float uni = fmaxf(px2 - px1, 0.0f) * fmaxf(py2 - py1, 0.0f)
                                  + fmaxf(gx2 - gx1, 0.0f) * fmaxf(gy2 - gy1, 0.0f) - inter;
                        float iou = inter / (uni + EPS_IOU);
                        best = fmaxf(best, iou);
                    }
                    unsigned long long key =
                        ((unsigned long long)__float_as_uint(best) << 32) |
                        (unsigned long long)(unsigned)(MAXB - tt);
                    if (key > bestkey) bestkey = key;
                }
                // in-group reduction (xor < 16 stays in the 16-lane group)
#pragma unroll
                for (int off = 1; off < 16; off <<= 1) {
                    unsigned long long ok = __shfl_xor(bestkey, off, 64);
                    if (ok > bestkey) bestkey = ok;
                    m0 |= __shfl_xor(m0, off, 64);
                    m1 |= __shfl_xor(m1, off, 64);
                    m2 |= __shfl_xor(m2, off, 64);
                }

                if ((unsigned)(bestkey & 0xffffffffu) == (unsigned)(MAXB - t)) {
                    // this group's target owns the cell
                    const float* pc = p + BB * 5;
                    float cl = 0.0f;
#pragma unroll
                    for (int j = 0; j < 5; ++j) {
                        int k = lane16 + 16 * j;
                        float x = pc[k];
                        unsigned mw = (k < 32) ? m0 : (k < 64) ? m1 : m2;
                        float gt = ((mw >> (k & 31)) & 1u) ? 1.0f : 0.0f;
                        cl += fmaxf(x, 0.0f) - x * gt + log1pf(expf(-fabsf(x)));
                    }
#pragma unroll
                    for (int off = 1; off < 16; off <<= 1)
                        cl += __shfl_xor(cl, off, 64);

                    if (lane16 == 0) {
                        float best_iou = __uint_as_float((unsigned)(bestkey >> 32));
                        float cx_rel = cxs - (float)col;
                        float cy_rel = cys - (float)row;

                        float p0[10];
#pragma unroll
                        for (int k = 0; k < 5; ++k) {
                            float2 v2 = *(const float2*)(p + 2 * k);
                            p0[2 * k] = v2.x; p0[2 * k + 1] = v2.y;
                        }

                        // replay argmax to get resp (bit-identical)
                        float gax1 = cx - gw * 0.5f, gay1 = cy - gh * 0.5f;
                        float gax2 = cx + gw * 0.5f, gay2 = cy + gh * 0.5f;
                        float bst = -1.0f; int resp = 0;
#pragma unroll
                        for (int j = 0; j < BB; ++j) {
                            float px = (p0[j * 5 + 0] + (float)col) * cell;
                            float py = (p0[j * 5 + 1] + (float)row) * cell;
                            float pw = p0[j * 5 + 2];
                            float ph = p0[j * 5 + 3];
                            float px1 = px - pw * 0.5f, py1 = py - ph * 0.5f;
                            float px2 = px + pw * 0.5f, py2 = py + ph * 0.5f;
                            float iw = fmaxf(fminf(px2, gax2) - fmaxf(px1, gax1), 0.0f);
                            float ih = fmaxf(fminf(py2, gay2) - fmaxf(py1, gay1), 0.0f);
                            float inter = iw * ih;
                            float uni = fmaxf(px2 - px1, 0.0f) * fmaxf(py2 - py1, 0.0f)
                                      + fmaxf(gax2 - gax1, 0.0f) * fmaxf(gay2 - gay1, 0.0f) - inter;
                            float iou = inter / (uni + EPS_IOU);
                            if (iou > bst) { bst = iou; resp = j; }
                        }

                        float bx = p0[resp * 5 + 0], by = p0[resp * 5 + 1];
                        float bw = p0[resp * 5 + 2], bh = p0[resp * 5 + 3];
                        float conf_r = p0[resp * 5 + 4];

                        float pax = (bx + (float)col) * cell;
                        float pay = (by + (float)row) * cell;
                        float paw = fabsf(bw), pah = fabsf(bh);
                        float gax = (cx_rel + (float)col) * cell;
                        float gay = (cy_rel + (float)row) * cell;

                        // CIoU (EPS = 1e-7 here)
                        float px1 = pax - paw * 0.5f, py1 = pay - pah * 0.5f;
                        float px2 = pax + paw * 0.5f, py2 = pay + pah * 0.5f;
                        float gx1 = gax - gw * 0.5f,  gy1 = gay - gh * 0.5f;
                        float gx2 = gax + gw * 0.5f,  gy2 = gay + gh * 0.5f;
                        float iw = fmaxf(fminf(px2, gx2) - fmaxf(px1, gx1), 0.0f);
                        float ih = fmaxf(fminf(py2, gy2) - fmaxf(py1, gy1), 0.0f);
                        float inter = iw * ih;
                        float area_p = fmaxf(px2 - px1, 0.0f) * fmaxf(py2 - py1, 0.0f);
                        float area_g = fmaxf(gx2 - gx1, 0.0f) * fmaxf(gy2 - gy1, 0.0f);
                        float uni = area_p + area_g - inter;
                        float iou = inter / (uni + EPSF);
                        float dx = pax - gax, dy = pay - gay;
                        float rho2 = dx * dx + dy * dy;
                        float cw = fmaxf(px2, gx2) - fminf(px1, gx1);
                        float chh = fmaxf(py2, gy2) - fminf(py1, gy1);
                        float c2 = cw * cw + chh * chh + EPSF;
                        float dv = atanf(gw / (gh + EPSF)) - atanf(paw / (pah + EPSF));
                        float v = FOUR_OVER_PI2 * dv * dv;
                        float alpha = v / (1.0f - iou + v + EPSF);
                        float ciou = 1.0f - iou + rho2 / c2 + alpha * v;

                        float d = conf_r - best_iou;
                        tot += cl + LAMBDA_COORD * ciou + d * d
                             - LAMBDA_NOOBJ * conf_r * conf_r;  // undo stream
                    }
                }
            }
        }
    }

    // block reduction -> partial[block] (no atomics)
    float v = tot;
#pragma unroll
    for (int off = 32; off > 0; off >>= 1)
        v += __shfl_down(v, off, 64);
    __shared__ float red[4];
    int lane = threadIdx.x & 63;
    int wid  = threadIdx.x >> 6;
    if (lane == 0) red[wid] = v;
    __syncthreads();
    if (threadIdx.x == 0)
        partial[blockIdx.x] = red[0] + red[1] + red[2] + red[3];
}

// Final reduction: one block sums the partials and writes out[0].
__global__ void __launch_bounds__(BLOCK)
reduce_k(const float* __restrict__ partial, float* __restrict__ out,
         int n, float inv_batch) {
    float s = 0.0f;
    for (int i = threadIdx.x; i < n; i += BLOCK)
        s += partial[i];
#pragma unroll
    for (int off = 32; off > 0; off >>= 1)
        s += __shfl_down(s, off, 64);
    __shared__ float red[4];
    int lane = threadIdx.x & 63;
    int wid  = threadIdx.x >> 6;
    if (lane == 0) red[wid] = s;
    __syncthreads();
    if (threadIdx.x == 0)
        out[0] = (red[0] + red[1] + red[2] + red[3]) * inv_batch;
}

extern "C" void kernel_launch(void* const* d_in, const int* in_sizes, int n_in,
                              void* d_out, int out_size, void* d_ws, size_t ws_size,
                              hipStream_t stream) {
    const float* pred = (const float*)d_in[0];
    const float* targ = (const float*)d_in[1];
    int batch = in_sizes[0] / (S * S * CH);
    int nt = batch * MAXB;
    int nf4 = in_sizes[0] / 4;   // total float4s in pred (90*784*batch / 4)

    int ng = (16 * nt + BLOCK - 1) / BLOCK;   // group blocks
    int nblocks = NSTREAM + ng;

    float* partial = (float*)d_ws;  // nblocks floats; written before read

    yolo_loss_k<<<nblocks, BLOCK, 0, stream>>>(pred, targ, partial, batch, nf4);
    reduce_k<<<1, BLOCK, 0, stream>>>(partial, (float*)d_out, nblocks,
                                      1.0f / (float)batch);
}